// Round 1
// baseline (2328.988 us; speedup 1.0000x reference)
//
#include <hip/hip_runtime.h>

#define N_NODES 100000
#define N_EDGES 640000
#define D 128

// ---------------------------------------------------------------------------
// Kernel 1: fold the two linear layers (no intermediate nonlinearity):
//   Wc = Wh @ Wo            (128x128)
//   bc = bh @ Wo + bo       (128)
// ---------------------------------------------------------------------------
__global__ void combine_weights(const float* __restrict__ Wh,
                                const float* __restrict__ bh,
                                const float* __restrict__ Wo,
                                const float* __restrict__ bo,
                                float* __restrict__ Wc,
                                float* __restrict__ bc) {
    int gid = blockIdx.x * blockDim.x + threadIdx.x;
    if (gid < D * D) {
        int i = gid >> 7;
        int j = gid & 127;
        float s = 0.f;
        #pragma unroll 4
        for (int k = 0; k < D; ++k)
            s = fmaf(Wh[i * D + k], Wo[k * D + j], s);
        Wc[gid] = s;
    } else if (gid < D * D + D) {
        int j = gid - D * D;
        float s = bo[j];
        #pragma unroll 4
        for (int k = 0; k < D; ++k)
            s = fmaf(bh[k], Wo[k * D + j], s);
        bc[j] = s;
    }
}

// ---------------------------------------------------------------------------
// Kernel 2: undirected edge scatter-add into agg (= d_out, pre-loaded with X).
// One thread per (edge, float4-chunk): 640000 * 32 = 20.48M threads.
// Gathers read the ORIGINAL X (reference semantics); scatters are f32 HW
// atomics (order-dependent rounding only, well within threshold).
// ---------------------------------------------------------------------------
__global__ __launch_bounds__(256)
void edge_scatter(const float4* __restrict__ X4,
                  const int* __restrict__ ra,
                  const int* __restrict__ rb,
                  float* __restrict__ agg) {
    unsigned gid = blockIdx.x * 256u + threadIdx.x;
    int e = gid >> 5;          // edge index
    int q = gid & 31;          // float4 chunk within the 128-wide row
    int a = ra[e];
    int b = rb[e];
    float4 xa = X4[(size_t)a * 32 + q];
    float4 xb = X4[(size_t)b * 32 + q];
    float* pb = agg + (size_t)b * D + q * 4;
    float* pa = agg + (size_t)a * D + q * 4;
    unsafeAtomicAdd(pb + 0, xa.x);
    unsafeAtomicAdd(pb + 1, xa.y);
    unsafeAtomicAdd(pb + 2, xa.z);
    unsafeAtomicAdd(pb + 3, xa.w);
    unsafeAtomicAdd(pa + 0, xb.x);
    unsafeAtomicAdd(pa + 1, xb.y);
    unsafeAtomicAdd(pa + 2, xb.z);
    unsafeAtomicAdd(pa + 3, xb.w);
}

// ---------------------------------------------------------------------------
// Kernel 3: in-place fused MLP:  agg <- relu(agg @ Wc + bc)
// Block = 256 threads, 32 rows per block (100000 = 3125 * 32 exactly).
// LDS: Wc (64 KB) + X tile (16 KB) = 80 KB -> 2 blocks/CU.
// Each thread: 4 rows x 4 cols register tile; 2 LDS bytes per FMA.
// In-place is safe: each output row depends only on its own input row,
// which is staged to LDS before any global write.
// ---------------------------------------------------------------------------
__global__ __launch_bounds__(256, 2)
void mlp_gemm(float* __restrict__ agg,
              const float* __restrict__ Wc,
              const float* __restrict__ bc) {
    __shared__ float Ws[D * D];     // 64 KB
    __shared__ float Xs[32][D];     // 16 KB
    const int t = threadIdx.x;
    const int rowbase = blockIdx.x * 32;

    // stage Wc (64 KB) cooperatively
    float4* Ws4 = (float4*)Ws;
    const float4* Wc4 = (const float4*)Wc;
    #pragma unroll
    for (int i = 0; i < D * D / 4 / 256; ++i)
        Ws4[t + i * 256] = Wc4[t + i * 256];

    // stage 32-row X tile (1024 float4)
    float4* Xs4 = (float4*)Xs;
    const float4* A4 = (const float4*)(agg + (size_t)rowbase * D);
    #pragma unroll
    for (int i = 0; i < 4; ++i)
        Xs4[t + i * 256] = A4[t + i * 256];

    const int tc = t & 31;    // column group: cols tc*4 .. tc*4+3
    const int tr = t >> 5;    // row group:   rows tr*4 .. tr*4+3
    float4 bias = ((const float4*)bc)[tc];

    __syncthreads();

    float acc[4][4];
    #pragma unroll
    for (int r = 0; r < 4; ++r)
        #pragma unroll
        for (int c = 0; c < 4; ++c) acc[r][c] = 0.f;

    #pragma unroll 2
    for (int k = 0; k < D; ++k) {
        float4 w = Ws4[k * (D / 4) + tc];
        #pragma unroll
        for (int r = 0; r < 4; ++r) {
            float x = Xs[tr * 4 + r][k];
            acc[r][0] = fmaf(x, w.x, acc[r][0]);
            acc[r][1] = fmaf(x, w.y, acc[r][1]);
            acc[r][2] = fmaf(x, w.z, acc[r][2]);
            acc[r][3] = fmaf(x, w.w, acc[r][3]);
        }
    }

    // epilogue: bias + relu, write back in place (rows owned by this block)
    #pragma unroll
    for (int r = 0; r < 4; ++r) {
        int row = rowbase + tr * 4 + r;
        float4 o;
        o.x = fmaxf(acc[r][0] + bias.x, 0.f);
        o.y = fmaxf(acc[r][1] + bias.y, 0.f);
        o.z = fmaxf(acc[r][2] + bias.z, 0.f);
        o.w = fmaxf(acc[r][3] + bias.w, 0.f);
        ((float4*)(agg + (size_t)row * D))[tc] = o;
    }
}

// ---------------------------------------------------------------------------
extern "C" void kernel_launch(void* const* d_in, const int* in_sizes, int n_in,
                              void* d_out, int out_size, void* d_ws, size_t ws_size,
                              hipStream_t stream) {
    const float* X  = (const float*)d_in[0];
    const float* Wh = (const float*)d_in[1];
    const float* bh = (const float*)d_in[2];
    const float* Wo = (const float*)d_in[3];
    const float* bo = (const float*)d_in[4];
    const int* ra   = (const int*)d_in[5];
    const int* rb   = (const int*)d_in[6];
    float* out = (float*)d_out;

    float* Wc = (float*)d_ws;                 // 128*128 f32 = 64 KB
    float* bc = (float*)d_ws + D * D;         // 128 f32

    // 1) fold weights
    combine_weights<<<(D * D + D + 255) / 256, 256, 0, stream>>>(Wh, bh, Wo, bo, Wc, bc);

    // 2) agg := X  (d_out doubles as the X_agg buffer: exactly N*128 floats)
    hipMemcpyAsync(out, X, (size_t)N_NODES * D * sizeof(float),
                   hipMemcpyDeviceToDevice, stream);

    // 3) undirected scatter-add of neighbor features
    {
        unsigned total = (unsigned)N_EDGES * 32u;          // 20.48M threads
        edge_scatter<<<total / 256, 256, 0, stream>>>((const float4*)X, ra, rb, out);
    }

    // 4) fused MLP in place: out = relu(agg @ Wc + bc)
    mlp_gemm<<<N_NODES / 32, 256, 0, stream>>>(out, Wc, bc);
}

// Round 6
// 423.356 us; speedup vs baseline: 5.5013x; 5.5013x over previous
//
#include <hip/hip_runtime.h>

#define N_NODES 100000
#define N_EDGES 640000
#define D 128
#define NB 98              // ceil(N_NODES / 1024) scan blocks

// ---------------------------------------------------------------------------
// Kernel 1: fold the two linear layers (no intermediate nonlinearity):
//   Wc = Wh @ Wo ; bc = bh @ Wo + bo
// ---------------------------------------------------------------------------
__global__ void combine_weights(const float* __restrict__ Wh,
                                const float* __restrict__ bh,
                                const float* __restrict__ Wo,
                                const float* __restrict__ bo,
                                float* __restrict__ Wc,
                                float* __restrict__ bc) {
    int gid = blockIdx.x * blockDim.x + threadIdx.x;
    if (gid < D * D) {
        int i = gid >> 7;
        int j = gid & 127;
        float s = 0.f;
        #pragma unroll 4
        for (int k = 0; k < D; ++k)
            s = fmaf(Wh[i * D + k], Wo[k * D + j], s);
        Wc[gid] = s;
    } else if (gid < D * D + D) {
        int j = gid - D * D;
        float s = bo[j];
        #pragma unroll 4
        for (int k = 0; k < D; ++k)
            s = fmaf(bh[k], Wo[k * D + j], s);
        bc[j] = s;
    }
}

// ---------------------------------------------------------------------------
// CSR build: count degrees -> scan -> fill adjacency
// ---------------------------------------------------------------------------
__global__ __launch_bounds__(256)
void count_deg(const int* __restrict__ ra, const int* __restrict__ rb,
               int* __restrict__ cnt) {
    int e = blockIdx.x * 256 + threadIdx.x;
    if (e < N_EDGES) {
        atomicAdd(&cnt[ra[e]], 1);
        atomicAdd(&cnt[rb[e]], 1);
    }
}

// per-1024-chunk sums
__global__ __launch_bounds__(256)
void sum_blocks(const int* __restrict__ cnt, int* __restrict__ partials) {
    __shared__ int sm[256];
    int t = threadIdx.x;
    int base = blockIdx.x * 1024 + t * 4;
    int tot = 0;
    #pragma unroll
    for (int i = 0; i < 4; ++i)
        if (base + i < N_NODES) tot += cnt[base + i];
    sm[t] = tot;
    __syncthreads();
    for (int d = 128; d > 0; d >>= 1) {
        if (t < d) sm[t] += sm[t + d];
        __syncthreads();
    }
    if (t == 0) partials[blockIdx.x] = sm[0];
}

// exclusive scan of the NB partials (tiny, serial)
__global__ void scan_partials(int* __restrict__ partials, int* __restrict__ off) {
    if (blockIdx.x == 0 && threadIdx.x == 0) {
        int run = 0;
        for (int b = 0; b < NB; ++b) {
            int v = partials[b];
            partials[b] = run;
            run += v;
        }
        off[N_NODES] = run;   // == 2*N_EDGES
    }
}

// per-chunk exclusive scan -> offsets (+ cursor copy)
__global__ __launch_bounds__(256)
void scan_blocks(const int* __restrict__ cnt, const int* __restrict__ partials,
                 int* __restrict__ off, int* __restrict__ cur) {
    __shared__ int sm[256];
    int t = threadIdx.x;
    int base = blockIdx.x * 1024 + t * 4;
    int c[4];
    int tot = 0;
    #pragma unroll
    for (int i = 0; i < 4; ++i) {
        c[i] = (base + i < N_NODES) ? cnt[base + i] : 0;
        tot += c[i];
    }
    sm[t] = tot;
    __syncthreads();
    // Hillis-Steele inclusive scan over 256 thread totals
    for (int d = 1; d < 256; d <<= 1) {
        int v = (t >= d) ? sm[t - d] : 0;
        __syncthreads();
        sm[t] += v;
        __syncthreads();
    }
    int excl = sm[t] - tot + partials[blockIdx.x];
    #pragma unroll
    for (int i = 0; i < 4; ++i) {
        int idx = base + i;
        if (idx < N_NODES) {
            off[idx] = excl;
            cur[idx] = excl;
            excl += c[i];
        }
    }
}

__global__ __launch_bounds__(256)
void fill_adj(const int* __restrict__ ra, const int* __restrict__ rb,
              int* __restrict__ cur, int* __restrict__ adj) {
    int e = blockIdx.x * 256 + threadIdx.x;
    if (e < N_EDGES) {
        int a = ra[e];
        int b = rb[e];
        adj[atomicAdd(&cur[a], 1)] = b;
        adj[atomicAdd(&cur[b], 1)] = a;
    }
}

// ---------------------------------------------------------------------------
// Gather aggregation: out[node] = X[node] + sum_{nbr} X[nbr]
// 32 lanes (one float4 chunk each) per node, 8 nodes per 256-thread block.
// No atomics; each output row written exactly once.
// ---------------------------------------------------------------------------
__global__ __launch_bounds__(256)
void gather_agg(const float4* __restrict__ X4, const int* __restrict__ off,
                const int* __restrict__ adj, float4* __restrict__ out4) {
    int node = blockIdx.x * 8 + (threadIdx.x >> 5);
    int lane = threadIdx.x & 31;
    float4 acc = X4[(size_t)node * 32 + lane];
    int s = off[node];
    int e = off[node + 1];
    int k = s;
    // unroll 2 neighbors for ILP (two independent L3 loads in flight)
    for (; k + 1 < e; k += 2) {
        int n0 = adj[k];
        int n1 = adj[k + 1];
        float4 v0 = X4[(size_t)n0 * 32 + lane];
        float4 v1 = X4[(size_t)n1 * 32 + lane];
        acc.x += v0.x; acc.y += v0.y; acc.z += v0.z; acc.w += v0.w;
        acc.x += v1.x; acc.y += v1.y; acc.z += v1.z; acc.w += v1.w;
    }
    if (k < e) {
        int n0 = adj[k];
        float4 v0 = X4[(size_t)n0 * 32 + lane];
        acc.x += v0.x; acc.y += v0.y; acc.z += v0.z; acc.w += v0.w;
    }
    out4[(size_t)node * 32 + lane] = acc;
}

// ---------------------------------------------------------------------------
// In-place fused MLP:  agg <- relu(agg @ Wc + bc)   (unchanged from R1)
// ---------------------------------------------------------------------------
__global__ __launch_bounds__(256, 2)
void mlp_gemm(float* __restrict__ agg,
              const float* __restrict__ Wc,
              const float* __restrict__ bc) {
    __shared__ float Ws[D * D];     // 64 KB
    __shared__ float Xs[32][D];     // 16 KB
    const int t = threadIdx.x;
    const int rowbase = blockIdx.x * 32;

    float4* Ws4 = (float4*)Ws;
    const float4* Wc4 = (const float4*)Wc;
    #pragma unroll
    for (int i = 0; i < D * D / 4 / 256; ++i)
        Ws4[t + i * 256] = Wc4[t + i * 256];

    float4* Xs4 = (float4*)Xs;
    const float4* A4 = (const float4*)(agg + (size_t)rowbase * D);
    #pragma unroll
    for (int i = 0; i < 4; ++i)
        Xs4[t + i * 256] = A4[t + i * 256];

    const int tc = t & 31;
    const int tr = t >> 5;
    float4 bias = ((const float4*)bc)[tc];

    __syncthreads();

    float acc[4][4];
    #pragma unroll
    for (int r = 0; r < 4; ++r)
        #pragma unroll
        for (int c = 0; c < 4; ++c) acc[r][c] = 0.f;

    #pragma unroll 2
    for (int k = 0; k < D; ++k) {
        float4 w = Ws4[k * (D / 4) + tc];
        #pragma unroll
        for (int r = 0; r < 4; ++r) {
            float x = Xs[tr * 4 + r][k];
            acc[r][0] = fmaf(x, w.x, acc[r][0]);
            acc[r][1] = fmaf(x, w.y, acc[r][1]);
            acc[r][2] = fmaf(x, w.z, acc[r][2]);
            acc[r][3] = fmaf(x, w.w, acc[r][3]);
        }
    }

    #pragma unroll
    for (int r = 0; r < 4; ++r) {
        int row = rowbase + tr * 4 + r;
        float4 o;
        o.x = fmaxf(acc[r][0] + bias.x, 0.f);
        o.y = fmaxf(acc[r][1] + bias.y, 0.f);
        o.z = fmaxf(acc[r][2] + bias.z, 0.f);
        o.w = fmaxf(acc[r][3] + bias.w, 0.f);
        ((float4*)(agg + (size_t)row * D))[tc] = o;
    }
}

// ---------------------------------------------------------------------------
extern "C" void kernel_launch(void* const* d_in, const int* in_sizes, int n_in,
                              void* d_out, int out_size, void* d_ws, size_t ws_size,
                              hipStream_t stream) {
    const float* X  = (const float*)d_in[0];
    const float* Wh = (const float*)d_in[1];
    const float* bh = (const float*)d_in[2];
    const float* Wo = (const float*)d_in[3];
    const float* bo = (const float*)d_in[4];
    const int* ra   = (const int*)d_in[5];
    const int* rb   = (const int*)d_in[6];
    float* out = (float*)d_out;

    // workspace layout (~6.7 MB)
    float* Wc = (float*)d_ws;                         // 16384 f32
    float* bc = Wc + D * D;                           // 128 f32
    int* cnt      = (int*)(bc + D);                   // N
    int* off      = cnt + N_NODES;                    // N+1
    int* cur      = off + N_NODES + 1;                // N
    int* adj      = cur + N_NODES;                    // 2E
    int* partials = adj + 2 * N_EDGES;                // NB

    // 1) fold weights
    combine_weights<<<(D * D + D + 255) / 256, 256, 0, stream>>>(Wh, bh, Wo, bo, Wc, bc);

    // 2) CSR build
    hipMemsetAsync(cnt, 0, N_NODES * sizeof(int), stream);
    count_deg<<<N_EDGES / 256, 256, 0, stream>>>(ra, rb, cnt);
    sum_blocks<<<NB, 256, 0, stream>>>(cnt, partials);
    scan_partials<<<1, 64, 0, stream>>>(partials, off);
    scan_blocks<<<NB, 256, 0, stream>>>(cnt, partials, off, cur);
    fill_adj<<<N_EDGES / 256, 256, 0, stream>>>(ra, rb, cur, adj);

    // 3) gather aggregation (no atomics): out = X + sum of neighbor rows
    gather_agg<<<N_NODES / 8, 256, 0, stream>>>((const float4*)X, off, adj, (float4*)out);

    // 4) fused MLP in place: out = relu(out @ Wc + bc)
    mlp_gemm<<<N_NODES / 32, 256, 0, stream>>>(out, Wc, bc);
}

// Round 8
// 347.468 us; speedup vs baseline: 6.7027x; 1.2184x over previous
//
#include <hip/hip_runtime.h>
#include <hip/hip_bf16.h>

#define N_NODES 100000
#define N_EDGES 640000
#define D 128
#define NB 98              // ceil(N_NODES / 1024) scan blocks

typedef unsigned short ushort_t;
typedef __attribute__((ext_vector_type(8))) short short8_t;   // 8 x bf16 (4 VGPR)
typedef __attribute__((ext_vector_type(4))) float floatx4;    // MFMA C/D

static __device__ __forceinline__ ushort_t f32_to_bf16(float f) {
    union { __hip_bfloat16 h; ushort_t u; } c;
    c.h = __float2bfloat16(f);          // RNE
    return c.u;
}
static __device__ __forceinline__ float bf16_to_f32(ushort_t u) {
    union { unsigned int i; float f; } c;
    c.i = ((unsigned int)u) << 16;
    return c.f;
}

// ---------------------------------------------------------------------------
// Fold the two linear layers:  Wc = Wh @ Wo ; bc = bh @ Wo + bo.
// Wc is stored TRANSPOSED and in bf16 (WcT[n][k] = Wc[k][n]) so the MFMA
// B-fragment (8 consecutive k for fixed n) is a contiguous 16 B load.
// ---------------------------------------------------------------------------
__global__ void combine_weights(const float* __restrict__ Wh,
                                const float* __restrict__ bh,
                                const float* __restrict__ Wo,
                                const float* __restrict__ bo,
                                ushort_t* __restrict__ WcT,
                                float* __restrict__ bc) {
    int gid = blockIdx.x * blockDim.x + threadIdx.x;
    if (gid < D * D) {
        int i = gid >> 7;          // k-index (row of Wc)
        int j = gid & 127;         // n-index (col of Wc)
        float s = 0.f;
        #pragma unroll 4
        for (int k = 0; k < D; ++k)
            s = fmaf(Wh[i * D + k], Wo[k * D + j], s);
        WcT[j * D + i] = f32_to_bf16(s);
    } else if (gid < D * D + D) {
        int j = gid - D * D;
        float s = bo[j];
        #pragma unroll 4
        for (int k = 0; k < D; ++k)
            s = fmaf(bh[k], Wo[k * D + j], s);
        bc[j] = s;
    }
}

// ---------------------------------------------------------------------------
// CSR build: count degrees -> scan -> fill adjacency  (unchanged from R6)
// ---------------------------------------------------------------------------
__global__ __launch_bounds__(256)
void count_deg(const int* __restrict__ ra, const int* __restrict__ rb,
               int* __restrict__ cnt) {
    int e = blockIdx.x * 256 + threadIdx.x;
    if (e < N_EDGES) {
        atomicAdd(&cnt[ra[e]], 1);
        atomicAdd(&cnt[rb[e]], 1);
    }
}

__global__ __launch_bounds__(256)
void sum_blocks(const int* __restrict__ cnt, int* __restrict__ partials) {
    __shared__ int sm[256];
    int t = threadIdx.x;
    int base = blockIdx.x * 1024 + t * 4;
    int tot = 0;
    #pragma unroll
    for (int i = 0; i < 4; ++i)
        if (base + i < N_NODES) tot += cnt[base + i];
    sm[t] = tot;
    __syncthreads();
    for (int d = 128; d > 0; d >>= 1) {
        if (t < d) sm[t] += sm[t + d];
        __syncthreads();
    }
    if (t == 0) partials[blockIdx.x] = sm[0];
}

__global__ void scan_partials(int* __restrict__ partials, int* __restrict__ off) {
    if (blockIdx.x == 0 && threadIdx.x == 0) {
        int run = 0;
        for (int b = 0; b < NB; ++b) {
            int v = partials[b];
            partials[b] = run;
            run += v;
        }
        off[N_NODES] = run;   // == 2*N_EDGES
    }
}

__global__ __launch_bounds__(256)
void scan_blocks(const int* __restrict__ cnt, const int* __restrict__ partials,
                 int* __restrict__ off, int* __restrict__ cur) {
    __shared__ int sm[256];
    int t = threadIdx.x;
    int base = blockIdx.x * 1024 + t * 4;
    int c[4];
    int tot = 0;
    #pragma unroll
    for (int i = 0; i < 4; ++i) {
        c[i] = (base + i < N_NODES) ? cnt[base + i] : 0;
        tot += c[i];
    }
    sm[t] = tot;
    __syncthreads();
    for (int d = 1; d < 256; d <<= 1) {
        int v = (t >= d) ? sm[t - d] : 0;
        __syncthreads();
        sm[t] += v;
        __syncthreads();
    }
    int excl = sm[t] - tot + partials[blockIdx.x];
    #pragma unroll
    for (int i = 0; i < 4; ++i) {
        int idx = base + i;
        if (idx < N_NODES) {
            off[idx] = excl;
            cur[idx] = excl;
            excl += c[i];
        }
    }
}

__global__ __launch_bounds__(256)
void fill_adj(const int* __restrict__ ra, const int* __restrict__ rb,
              int* __restrict__ cur, int* __restrict__ adj) {
    int e = blockIdx.x * 256 + threadIdx.x;
    if (e < N_EDGES) {
        int a = ra[e];
        int b = rb[e];
        adj[atomicAdd(&cur[a], 1)] = b;
        adj[atomicAdd(&cur[b], 1)] = a;
    }
}

// ---------------------------------------------------------------------------
// MFMA GEMM over 16x16x32 bf16 fragments.
//   MODE 0:  Ybf = bf16( A_f32 @ Wc )          (A = X, output bf16 to ws)
//   MODE 1:  Fout = relu( Fout @ Wc + bc )     (in-place on d_out, f32 out)
// Block = 256 threads = 4 waves; each wave computes a 16-row x 128-col strip.
// 100000 = 6250 * 16, so waves are always full (guard only whole waves).
// Fragment layouts (guide §3, m89/m91-verified):
//   A: lane holds A[m = base+(l&15)][k0..k0+7], k0 = kc*32 + (l>>4)*8
//   B: lane holds B[k0..k0+7][n],  n from WcT row (transposed, contiguous)
//   C/D: col = l&15, row = (l>>4)*4 + reg
// LDS: WcT staged as [128][136] bf16 (pad 8 -> 2-way bank alias only = free).
// In-place safety (MODE 1): all A-fragment loads are issued before MFMAs,
// whose s_waitcnt completes them wave-wide before any epilogue store; each
// row is read/written by exactly one wave.
// ---------------------------------------------------------------------------
template<int MODE>
__global__ __launch_bounds__(256)
void gemm_mfma(const float* __restrict__ A, ushort_t* __restrict__ Ybf,
               float* Fout, const ushort_t* __restrict__ WcT,
               const float* __restrict__ bc) {
    __shared__ ushort_t Ws[D][136];
    const int t = threadIdx.x;

    // stage WcT (128x128 bf16 = 32 KB) into padded LDS
    {
        const short8_t* src = (const short8_t*)WcT;   // 2048 groups of 8
        #pragma unroll
        for (int i = 0; i < 8; ++i) {
            int g = t + i * 256;
            int n = g >> 4;
            int k = (g & 15) * 8;
            *(short8_t*)(&Ws[n][k]) = src[g];
        }
    }
    __syncthreads();

    const int wave = t >> 6;
    const int lane = t & 63;
    const int rowBase = (blockIdx.x * 4 + wave) * 16;
    if (rowBase >= N_NODES) return;      // whole-wave uniform guard

    const int m = rowBase + (lane & 15);
    const int kgrp = lane >> 4;          // 0..3
    const float* arow = (MODE == 0 ? A : (const float*)Fout) + (size_t)m * D;

    // load + convert the 4 A-fragments (issued before any MFMA/store)
    short8_t afrag[4];
    #pragma unroll
    for (int kc = 0; kc < 4; ++kc) {
        int k0 = kc * 32 + kgrp * 8;
        float4 lo = *(const float4*)(arow + k0);
        float4 hi = *(const float4*)(arow + k0 + 4);
        short8_t f;
        f[0] = (short)f32_to_bf16(lo.x);
        f[1] = (short)f32_to_bf16(lo.y);
        f[2] = (short)f32_to_bf16(lo.z);
        f[3] = (short)f32_to_bf16(lo.w);
        f[4] = (short)f32_to_bf16(hi.x);
        f[5] = (short)f32_to_bf16(hi.y);
        f[6] = (short)f32_to_bf16(hi.z);
        f[7] = (short)f32_to_bf16(hi.w);
        afrag[kc] = f;
    }

    floatx4 acc[8];
    #pragma unroll
    for (int nt = 0; nt < 8; ++nt)
        acc[nt] = (floatx4){0.f, 0.f, 0.f, 0.f};

    #pragma unroll
    for (int kc = 0; kc < 4; ++kc) {
        const int k0 = kc * 32 + kgrp * 8;
        #pragma unroll
        for (int nt = 0; nt < 8; ++nt) {
            const int n = nt * 16 + (lane & 15);
            short8_t b = *(const short8_t*)(&Ws[n][k0]);
            acc[nt] = __builtin_amdgcn_mfma_f32_16x16x32_bf16(afrag[kc], b, acc[nt], 0, 0, 0);
        }
    }

    // epilogue: C/D mapping col = lane&15, row = (lane>>4)*4 + j
    const int orow0 = rowBase + (lane >> 4) * 4;
    const int col0 = lane & 15;
    if (MODE == 0) {
        #pragma unroll
        for (int j = 0; j < 4; ++j) {
            size_t base = (size_t)(orow0 + j) * D;
            #pragma unroll
            for (int nt = 0; nt < 8; ++nt)
                Ybf[base + nt * 16 + col0] = f32_to_bf16(acc[nt][j]);
        }
    } else {
        #pragma unroll
        for (int j = 0; j < 4; ++j) {
            size_t base = (size_t)(orow0 + j) * D;
            #pragma unroll
            for (int nt = 0; nt < 8; ++nt) {
                float v = acc[nt][j] + bc[nt * 16 + col0];
                Fout[base + nt * 16 + col0] = fmaxf(v, 0.f);
            }
        }
    }
}

// ---------------------------------------------------------------------------
// Gather aggregation over CSR.
//   BF16IN = true : rows of Ybf (bf16, 256 B), epilogue += bc then relu -> f32 out
//   BF16IN = false: rows of X (f32, 512 B), plain sum -> f32 out (agg buffer)
// 32 lanes per node, 8 nodes per 256-thread block. No atomics.
// ---------------------------------------------------------------------------
template<bool BF16IN>
__global__ __launch_bounds__(256)
void gather_k(const ushort_t* __restrict__ Y, const float* __restrict__ Xf,
              const int* __restrict__ off, const int* __restrict__ adj,
              const float* __restrict__ bc, float* __restrict__ out) {
    const int node = blockIdx.x * 8 + (threadIdx.x >> 5);
    const int lane = threadIdx.x & 31;
    float4 acc;
    if (BF16IN) {
        ushort4 u = *(const ushort4*)(Y + (size_t)node * D + lane * 4);
        acc.x = bf16_to_f32(u.x); acc.y = bf16_to_f32(u.y);
        acc.z = bf16_to_f32(u.z); acc.w = bf16_to_f32(u.w);
    } else {
        acc = *(const float4*)(Xf + (size_t)node * D + lane * 4);
    }
    const int s = off[node];
    const int e = off[node + 1];
    int k = s;
    for (; k + 1 < e; k += 2) {
        int n0 = adj[k];
        int n1 = adj[k + 1];
        if (BF16IN) {
            ushort4 u0 = *(const ushort4*)(Y + (size_t)n0 * D + lane * 4);
            ushort4 u1 = *(const ushort4*)(Y + (size_t)n1 * D + lane * 4);
            acc.x += bf16_to_f32(u0.x); acc.y += bf16_to_f32(u0.y);
            acc.z += bf16_to_f32(u0.z); acc.w += bf16_to_f32(u0.w);
            acc.x += bf16_to_f32(u1.x); acc.y += bf16_to_f32(u1.y);
            acc.z += bf16_to_f32(u1.z); acc.w += bf16_to_f32(u1.w);
        } else {
            float4 v0 = *(const float4*)(Xf + (size_t)n0 * D + lane * 4);
            float4 v1 = *(const float4*)(Xf + (size_t)n1 * D + lane * 4);
            acc.x += v0.x; acc.y += v0.y; acc.z += v0.z; acc.w += v0.w;
            acc.x += v1.x; acc.y += v1.y; acc.z += v1.z; acc.w += v1.w;
        }
    }
    if (k < e) {
        int n0 = adj[k];
        if (BF16IN) {
            ushort4 u0 = *(const ushort4*)(Y + (size_t)n0 * D + lane * 4);
            acc.x += bf16_to_f32(u0.x); acc.y += bf16_to_f32(u0.y);
            acc.z += bf16_to_f32(u0.z); acc.w += bf16_to_f32(u0.w);
        } else {
            float4 v0 = *(const float4*)(Xf + (size_t)n0 * D + lane * 4);
            acc.x += v0.x; acc.y += v0.y; acc.z += v0.z; acc.w += v0.w;
        }
    }
    if (BF16IN) {
        float4 b = *(const float4*)(bc + lane * 4);
        acc.x = fmaxf(acc.x + b.x, 0.f);
        acc.y = fmaxf(acc.y + b.y, 0.f);
        acc.z = fmaxf(acc.z + b.z, 0.f);
        acc.w = fmaxf(acc.w + b.w, 0.f);
    }
    *(float4*)(out + (size_t)node * D + lane * 4) = acc;
}

// ---------------------------------------------------------------------------
extern "C" void kernel_launch(void* const* d_in, const int* in_sizes, int n_in,
                              void* d_out, int out_size, void* d_ws, size_t ws_size,
                              hipStream_t stream) {
    const float* X  = (const float*)d_in[0];
    const float* Wh = (const float*)d_in[1];
    const float* bh = (const float*)d_in[2];
    const float* Wo = (const float*)d_in[3];
    const float* bo = (const float*)d_in[4];
    const int* ra   = (const int*)d_in[5];
    const int* rb   = (const int*)d_in[6];
    float* out = (float*)d_out;

    // workspace layout (all chunks 16 B aligned)
    char* p = (char*)d_ws;
    ushort_t* WcT = (ushort_t*)p;  p += (size_t)D * D * 2;          // 32 KB bf16
    float* bc     = (float*)p;     p += (size_t)D * 4;              // 512 B
    int* cnt      = (int*)p;       p += (size_t)N_NODES * 4;        // 400 KB
    int* off      = (int*)p;       p += (size_t)(N_NODES + 4) * 4;  // 400 KB (padded)
    int* cur      = (int*)p;       p += (size_t)N_NODES * 4;        // 400 KB
    int* adj      = (int*)p;       p += (size_t)2 * N_EDGES * 4;    // 5.12 MB
    int* partials = (int*)p;       p += 448;                        // NB ints, padded
    ushort_t* Ybf = (ushort_t*)p;  p += (size_t)N_NODES * D * 2;    // 25.6 MB
    const size_t need = (size_t)(p - (char*)d_ws);
    const bool bigws = ws_size >= need;   // same branch every call (ws_size fixed)

    // 1) fold weights -> WcT (bf16, transposed) + bc (f32)
    combine_weights<<<(D * D + D + 255) / 256, 256, 0, stream>>>(Wh, bh, Wo, bo, WcT, bc);

    // 2) CSR build
    hipMemsetAsync(cnt, 0, N_NODES * sizeof(int), stream);
    count_deg<<<N_EDGES / 256, 256, 0, stream>>>(ra, rb, cnt);
    sum_blocks<<<NB, 256, 0, stream>>>(cnt, partials);
    scan_partials<<<1, 64, 0, stream>>>(partials, off);
    scan_blocks<<<NB, 256, 0, stream>>>(cnt, partials, off, cur);
    fill_adj<<<N_EDGES / 256, 256, 0, stream>>>(ra, rb, cur, adj);

    const int gemm_grid = (N_NODES + 63) / 64;   // 4 waves x 16 rows per block

    if (bigws) {
        // Path A: GEMM-first. Y = bf16(X @ Wc); out = relu(gather(Y) + bc).
        gemm_mfma<0><<<gemm_grid, 256, 0, stream>>>(X, Ybf, nullptr, WcT, bc);
        gather_k<true><<<N_NODES / 8, 256, 0, stream>>>(Ybf, nullptr, off, adj, bc, out);
    } else {
        // Path B: aggregate-first (f32) into d_out, then in-place MFMA GEMM.
        gather_k<false><<<N_NODES / 8, 256, 0, stream>>>(nullptr, X, off, adj, nullptr, out);
        gemm_mfma<1><<<gemm_grid, 256, 0, stream>>>(nullptr, nullptr, out, WcT, bc);
    }
}